// Round 7
// baseline (181.877 us; speedup 1.0000x reference)
//
#include <hip/hip_runtime.h>

typedef unsigned short u16;
typedef unsigned long long u64;
typedef __bf16 bf16x8 __attribute__((ext_vector_type(8)));
typedef float floatx4 __attribute__((ext_vector_type(4)));

#define B_   2
#define T_   1024
#define DIM_ 1024
#define H_   8
#define DH_  64
#define E_   5

// c1 column layout: [0,512) q | [512,1024) k | [1024,3584) vexp (h,e,dh)
#define N1   3584
#define M_   2048
#define KOUT 2560

__device__ __forceinline__ u16 f2bf(float f) {
  union { float f; unsigned u; } v; v.f = f;
  unsigned r = v.u + 0x7FFFu + ((v.u >> 16) & 1u);
  return (u16)(r >> 16);
}
__device__ __forceinline__ float bf2f(u16 h) {
  union { unsigned u; float f; } v; v.u = ((unsigned)h) << 16;
  return v.f;
}

__device__ __forceinline__ void async_cp16(const void* g, void* l) {
  __builtin_amdgcn_global_load_lds(
      (const __attribute__((address_space(1))) unsigned int*)g,
      (__attribute__((address_space(3))) unsigned int*)l, 16, 0, 0);
}

// ---------------- preamble: [blocks 0..255] logits+topk (+xb emit) | [256..6399] weight prep ----------------
#define XI(r, k) ((r) * 1088 + (k) + (((k) >> 6) << 2))

__global__ __launch_bounds__(256)
void preamble_kernel(const float* __restrict__ x, const float* __restrict__ Wq,
                     const float* __restrict__ Wk, const float* __restrict__ Wv,
                     const float* __restrict__ Ws, const float* __restrict__ Wd,
                     const float* __restrict__ Wo,
                     u16* __restrict__ WT, u16* __restrict__ WoT,
                     float* __restrict__ ssg, u64* __restrict__ sdb,
                     u16* __restrict__ xb) {
  __shared__ __align__(16) char smem[47744];
  const int bx = blockIdx.x;
  const int tid = threadIdx.x;

  if (bx >= 256) {                    // ---- weight prep ----
    const int pb = bx - 256;
    const int kx = pb & 31, nt = pb >> 5;
    if (nt < 112) {
      float (*tile)[33] = (float(*)[33])smem;
      int k0 = kx * 32;
      const float* W; int N, n0, nofs;
      if (nt < 16)      { W = Wq; N = 512;  n0 = nt * 32;        nofs = 0; }
      else if (nt < 32) { W = Wk; N = 512;  n0 = (nt - 16) * 32; nofs = 512; }
      else              { W = Wv; N = 2560; n0 = (nt - 32) * 32; nofs = 1024; }
      int tx = tid & 31, ty = tid >> 5;
      #pragma unroll
      for (int i = 0; i < 32; i += 8)
        tile[ty + i][tx] = W[(size_t)(k0 + ty + i) * N + n0 + tx];
      __syncthreads();
      #pragma unroll
      for (int i = 0; i < 32; i += 8)
        WT[(size_t)(nofs + n0 + ty + i) * 1024 + k0 + tx] = f2bf(tile[tx][ty + i]);
    } else {
      int id = (nt - 112) * 32 + kx;
      int i = id * 256 + tid;
      int c4 = i & 15;
      int t  = i >> 4;
      int d  = t / 40;
      int he = t - d * 40;
      float4 v = *(const float4*)(Wo + ((size_t)(he * 1024 + d) * 64 + c4 * 4));
      union { u16 s[4]; uint2 u; } o;
      o.s[0] = f2bf(v.x); o.s[1] = f2bf(v.y); o.s[2] = f2bf(v.z); o.s[3] = f2bf(v.w);
      *(uint2*)(WoT + (size_t)d * KOUT + he * 64 + c4 * 4) = o.u;
    }
    return;
  }

  // ---- logits + topk, rows bt0..bt0+7 ----
  float* xs = (float*)smem;
  float* ps = xs + 8 * 1088;
  float* lg = ps + 4 * 640;
  unsigned char* mb = (unsigned char*)(lg + 640);
  const int bt0 = bx * 8;

  for (int i = tid; i < 2048; i += 256) {
    int r = i >> 8, j = i & 255;
    float4 v = ((const float4*)(x + (size_t)(bt0 + r) * 1024))[j];
    *(float4*)(xs + XI(r, j * 4)) = v;
    union { u16 h[4]; uint2 u; } o;
    o.h[0] = f2bf(v.x); o.h[1] = f2bf(v.y); o.h[2] = f2bf(v.z); o.h[3] = f2bf(v.w);
    *(uint2*)(xb + (size_t)(bt0 + r) * 1024 + j * 4) = o.u;
  }
  __syncthreads();

  const int cx = tid & 15;
  const int ky = tid >> 4;
  float acc[8][5];
  #pragma unroll
  for (int r = 0; r < 8; ++r)
    #pragma unroll
    for (int c = 0; c < 5; ++c) acc[r][c] = 0.f;

  for (int q4 = 0; q4 < 16; ++q4) {
    const int k = ky * 64 + q4 * 4;
    float4 xr[8];
    #pragma unroll
    for (int r = 0; r < 8; ++r) xr[r] = *(const float4*)(xs + XI(r, k));
    #pragma unroll
    for (int c = 0; c < 5; ++c) {
      const int col = cx * 5 + c;
      const float* Wp = (col < 40) ? (Ws + col) : (Wd + col - 40);
      float w0 = Wp[(size_t)(k + 0) * 40], w1 = Wp[(size_t)(k + 1) * 40];
      float w2 = Wp[(size_t)(k + 2) * 40], w3 = Wp[(size_t)(k + 3) * 40];
      #pragma unroll
      for (int r = 0; r < 8; ++r) {
        float a = acc[r][c];
        a = fmaf(xr[r].x, w0, a); a = fmaf(xr[r].y, w1, a);
        a = fmaf(xr[r].z, w2, a); a = fmaf(xr[r].w, w3, a);
        acc[r][c] = a;
      }
    }
  }

  #pragma unroll
  for (int r = 0; r < 8; ++r)
    #pragma unroll
    for (int c = 0; c < 5; ++c) {
      float a = acc[r][c];
      a += __shfl_xor(a, 16);
      a += __shfl_xor(a, 32);
      acc[r][c] = a;
    }
  const int w = tid >> 6, lane = tid & 63;
  if (lane < 16) {
    #pragma unroll
    for (int r = 0; r < 8; ++r)
      #pragma unroll
      for (int c = 0; c < 5; ++c)
        ps[w * 640 + r * 80 + lane * 5 + c] = acc[r][c];
  }
  __syncthreads();
  for (int idx = tid; idx < 640; idx += 256)
    lg[idx] = ps[idx] + ps[640 + idx] + ps[1280 + idx] + ps[1920 + idx];
  __syncthreads();

  if (tid < 128) {
    const int r = tid >> 4, h = (tid >> 1) & 7, side = tid & 1;
    float z[E_], g[E_]; bool sel[E_];
    #pragma unroll
    for (int e = 0; e < E_; ++e) {
      z[e] = lg[r * 80 + side * 40 + h * E_ + e];
      g[e] = 1.f / (1.f + __expf(-z[e]));
      sel[e] = false;
    }
    #pragma unroll
    for (int it = 0; it < 3; ++it) {
      int bi = 0; float bv = -3e38f;
      #pragma unroll
      for (int e = 0; e < E_; ++e)
        if (!sel[e] && z[e] > bv) { bv = z[e]; bi = e; }
      sel[bi] = true;
    }
    if (side == 0) {
      #pragma unroll
      for (int e = 0; e < E_; ++e)
        ssg[(size_t)(bt0 + r) * 40 + h * E_ + e] = sel[e] ? g[e] : 0.f;
    } else {
      unsigned bits = 0;
      #pragma unroll
      for (int e = 0; e < E_; ++e) bits |= (sel[e] ? 1u : 0u) << e;
      mb[r * 8 + h] = (unsigned char)bits;
    }
  }
  __syncthreads();
  if (tid < 8) {
    u64 m = 0;
    #pragma unroll
    for (int hh = 0; hh < 8; ++hh) m |= (u64)mb[tid * 8 + hh] << (5 * hh);
    sdb[bt0 + tid] = m;
  }
}

// ---------------- MFMA GEMM, 128x64 tile, BK=64, swizzled LDS, C = A @ B^T ----------------
// 896 blocks for N=3584 -> 3.5 blocks/CU; __launch_bounds__(256,3) for co-residency.

__global__ __launch_bounds__(256, 3)
void gemm4w_kernel(const u16* __restrict__ A, const u16* __restrict__ Bm,
                   u16* __restrict__ C, int N, int Kd) {
  __shared__ __align__(16) u16 As[128 * 64];   // 16 KB
  __shared__ __align__(16) u16 Bs[64 * 64];    //  8 KB
  const int tid = threadIdx.x;
  const int w = tid >> 6, lane = tid & 63;
  const int ln15 = lane & 15, quad = lane >> 4;
  const int bm0 = blockIdx.x * 128, bn0 = blockIdx.y * 64;
  const int r8 = lane >> 3;
  const int g8 = ((lane & 7) ^ r8) * 8;
  const int swz = ln15 & 7;

  floatx4 acc[2][4];
  #pragma unroll
  for (int i = 0; i < 2; ++i)
    #pragma unroll
    for (int j = 0; j < 4; ++j) acc[i][j] = (floatx4){0.f, 0.f, 0.f, 0.f};

  for (int k0 = 0; k0 < Kd; k0 += 64) {
    __syncthreads();
    #pragma unroll
    for (int j = 0; j < 4; ++j) {
      int i = w * 4 + j;                        // A: 16 groups of 8 rows
      async_cp16(A + (size_t)(bm0 + i * 8 + r8) * Kd + k0 + g8, (char*)As + i * 1024);
    }
    #pragma unroll
    for (int j = 0; j < 2; ++j) {
      int i = w * 2 + j;                        // B: 8 groups of 8 rows
      async_cp16(Bm + (size_t)(bn0 + i * 8 + r8) * Kd + k0 + g8, (char*)Bs + i * 1024);
    }
    __builtin_amdgcn_s_waitcnt(0);
    __syncthreads();

    #pragma unroll
    for (int t = 0; t < 2; ++t) {
      bf16x8 af[2], bf[4];
      #pragma unroll
      for (int mt = 0; mt < 2; ++mt)
        af[mt] = *(const bf16x8*)(As + (w * 32 + mt * 16 + ln15) * 64 + (((t * 4 + quad) ^ swz) * 8));
      #pragma unroll
      for (int nt = 0; nt < 4; ++nt)
        bf[nt] = *(const bf16x8*)(Bs + (nt * 16 + ln15) * 64 + (((t * 4 + quad) ^ swz) * 8));
      #pragma unroll
      for (int mt = 0; mt < 2; ++mt)
        #pragma unroll
        for (int nt = 0; nt < 4; ++nt)
          acc[mt][nt] = __builtin_amdgcn_mfma_f32_16x16x32_bf16(af[mt], bf[nt], acc[mt][nt], 0, 0, 0);
    }
  }

  #pragma unroll
  for (int mt = 0; mt < 2; ++mt)
    #pragma unroll
    for (int nt = 0; nt < 4; ++nt)
      #pragma unroll
      for (int r = 0; r < 4; ++r) {
        int m = bm0 + w * 32 + mt * 16 + quad * 4 + r;
        int n = bn0 + nt * 16 + ln15;
        C[(size_t)m * N + n] = f2bf(acc[mt][nt][r]);
      }
}

// ---------------- GEMM2 fused: 128x64 tile, split-K=2, sd-gated A ----------------

__global__ __launch_bounds__(256, 3)
void gemm2f_kernel(const u16* __restrict__ o_bh, const u16* __restrict__ WoT,
                   const u64* __restrict__ sdb, u16* __restrict__ Pk) {
  __shared__ __align__(16) u16 As[128 * 64];
  __shared__ __align__(16) u16 Bs[64 * 64];
  const int tid = threadIdx.x;
  const int w = tid >> 6, lane = tid & 63;
  const int ln15 = lane & 15, quad = lane >> 4;
  const int bm0 = blockIdx.x * 128, bn0 = blockIdx.y * 64;
  const int b = bm0 >> 10;
  const int t_base = bm0 & 1023;
  const int r8 = lane >> 3;
  const int g8 = ((lane & 7) ^ r8) * 8;
  const int swz = ln15 & 7;
  const int kbeg = blockIdx.z * 1280;

  u64 sdr[2];
  #pragma unroll
  for (int mt = 0; mt < 2; ++mt)
    sdr[mt] = sdb[bm0 + w * 32 + mt * 16 + ln15];

  floatx4 acc[2][4];
  #pragma unroll
  for (int i = 0; i < 2; ++i)
    #pragma unroll
    for (int j = 0; j < 4; ++j) acc[i][j] = (floatx4){0.f, 0.f, 0.f, 0.f};

  for (int k0 = kbeg; k0 < kbeg + 1280; k0 += 64) {
    const int he = k0 >> 6;
    const int h = (he * 205) >> 10;              // he / 5
    const u16* abase = o_bh + (size_t)((b * 8 + h) * 1024 + t_base) * 64;
    __syncthreads();
    #pragma unroll
    for (int j = 0; j < 4; ++j) {
      int i = w * 4 + j;
      async_cp16(abase + (size_t)(i * 8 + r8) * 64 + g8, (char*)As + i * 1024);
    }
    #pragma unroll
    for (int j = 0; j < 2; ++j) {
      int i = w * 2 + j;
      async_cp16(WoT + (size_t)(bn0 + i * 8 + r8) * KOUT + k0 + g8, (char*)Bs + i * 1024);
    }
    __builtin_amdgcn_s_waitcnt(0);
    __syncthreads();

    union { uint4 u; bf16x8 v; } z8; z8.u = (uint4){0u, 0u, 0u, 0u};
    #pragma unroll
    for (int t = 0; t < 2; ++t) {
      bf16x8 af[2], bf[4];
      #pragma unroll
      for (int mt = 0; mt < 2; ++mt) {
        af[mt] = *(const bf16x8*)(As + (w * 32 + mt * 16 + ln15) * 64 + (((t * 4 + quad) ^ swz) * 8));
        if (!((sdr[mt] >> he) & 1)) af[mt] = z8.v;
      }
      #pragma unroll
      for (int nt = 0; nt < 4; ++nt)
        bf[nt] = *(const bf16x8*)(Bs + (nt * 16 + ln15) * 64 + (((t * 4 + quad) ^ swz) * 8));
      #pragma unroll
      for (int mt = 0; mt < 2; ++mt)
        #pragma unroll
        for (int nt = 0; nt < 4; ++nt)
          acc[mt][nt] = __builtin_amdgcn_mfma_f32_16x16x32_bf16(af[mt], bf[nt], acc[mt][nt], 0, 0, 0);
    }
  }

  u16* Cz = Pk + (size_t)blockIdx.z * M_ * 1024;
  #pragma unroll
  for (int mt = 0; mt < 2; ++mt)
    #pragma unroll
    for (int nt = 0; nt < 4; ++nt)
      #pragma unroll
      for (int r = 0; r < 4; ++r) {
        int m = bm0 + w * 32 + mt * 16 + quad * 4 + r;
        int n = bn0 + nt * 16 + ln15;
        Cz[(size_t)m * 1024 + n] = f2bf(acc[mt][nt][r]);
      }
}

// reduce 2 bf16 split-K partials -> fp32 out
__global__ void reduce2_kernel(const u16* __restrict__ Pk, float* __restrict__ out) {
  int i = blockIdx.x * 256 + threadIdx.x;
  size_t base = (size_t)i * 8;
  float s[8] = {0.f, 0.f, 0.f, 0.f, 0.f, 0.f, 0.f, 0.f};
  #pragma unroll
  for (int z = 0; z < 2; ++z) {
    union { uint4 v; u16 h[8]; } u;
    u.v = *(const uint4*)(Pk + (size_t)z * M_ * 1024 + base);
    #pragma unroll
    for (int c = 0; c < 8; ++c) s[c] += bf2f(u.h[c]);
  }
  float4 o0 = {s[0], s[1], s[2], s[3]}, o1 = {s[4], s[5], s[6], s[7]};
  *(float4*)(out + base) = o0;
  *(float4*)(out + base + 4) = o1;
}

// ---------------- fused V-mix + transpose ----------------

__global__ __launch_bounds__(256)
void vmix_tr_kernel(const u16* __restrict__ c1, const float* __restrict__ ssg,
                    u16* __restrict__ vT) {
  __shared__ u16 tile[32][33];
  const int bh = blockIdx.x;
  const int b = bh >> 3, h = bh & 7;
  const int t0 = blockIdx.y * 32, d0 = blockIdx.z * 32;
  const int dh = threadIdx.x & 31, tl = threadIdx.x >> 5;
  #pragma unroll
  for (int i = 0; i < 4; ++i) {
    int trow = tl + i * 8;
    size_t bt = (size_t)b * T_ + t0 + trow;
    const u16* ve = c1 + bt * N1 + 1024 + h * (E_ * 64) + d0 + dh;
    const float* g = ssg + bt * 40 + h * E_;
    float s = 0.f;
    #pragma unroll
    for (int e = 0; e < E_; ++e) s = fmaf(g[e], bf2f(ve[e * 64]), s);
    tile[trow][dh] = f2bf(s);
  }
  __syncthreads();
  #pragma unroll
  for (int i = 0; i < 4; ++i) {
    int d = d0 + tl + i * 8;
    vT[((size_t)(b * H_ + h) * DH_ + d) * T_ + t0 + dh] = tile[dh][tl + i * 8];
  }
}

// ---------------- flash attention: balanced 32-row Q tiles, wave-pairs split kt ----------------

__global__ __launch_bounds__(256)
void attn_kernel(const u16* __restrict__ c1, const u16* __restrict__ vT,
                 u16* __restrict__ o_bh) {
  __shared__ __align__(16) u16 Qs[32 * 64];
  __shared__ __align__(16) u16 Ks[2][64 * 64];
  __shared__ __align__(16) u16 Vs[2][64 * 64];
  __shared__ __align__(16) u16 Ps[2][32 * 72];
  __shared__ float Om[2][32][68];
  __shared__ float Ml[2][32], Ll[2][32];
  const int bx = blockIdx.x;
  const int qi = (bx & 1) ? (bx >> 1) : (31 - (bx >> 1));
  const int bh = blockIdx.y;
  const int b = bh >> 3, h = bh & 7;
  const int tid = threadIdx.x;
  const int w = tid >> 6, lane = tid & 63;
  const int ln15 = lane & 15, quad = lane >> 4;
  const int hh = w >> 1, wq = w & 1;
  const int q0 = qi * 32;
  const int nkt = (qi >> 1) + 1;
  const int h0n = (nkt + 1) >> 1;
  const int r8 = lane >> 3;
  const int g8 = ((lane & 7) ^ ((lane >> 3) & 7)) * 8;
  const int swz = ln15 & 7;

  async_cp16(c1 + (size_t)(b * T_ + q0 + w * 8 + r8) * N1 + h * DH_ + g8,
             (char*)Qs + w * 1024);

  floatx4 O[4];
  float m_st[4], l_st[4];
  #pragma unroll
  for (int j = 0; j < 4; ++j) {
    O[j] = (floatx4){0.f, 0.f, 0.f, 0.f};
    m_st[j] = -3e38f; l_st[j] = 0.f;
  }
  const int qrow = q0 + wq * 16 + quad * 4;

  for (int j = 0; j < h0n; ++j) {
    const int myt = hh ? (h0n + j) : j;
    const bool act = (hh == 0) || (h0n + j < nkt);
    __syncthreads();
    if (w < 2 || h0n + j < nkt) {
      const int tk = (w < 2 ? j : h0n + j) * 64;
      if ((w & 1) == 0) {
        #pragma unroll
        for (int i = 0; i < 8; ++i)
          async_cp16(c1 + (size_t)(b * T_ + tk + i * 8 + r8) * N1 + 512 + h * DH_ + g8,
                     (char*)Ks[w >> 1] + i * 1024);
      } else {
        #pragma unroll
        for (int i = 0; i < 8; ++i)
          async_cp16(vT + (size_t)((b * H_ + h) * DH_ + i * 8 + r8) * T_ + tk + g8,
                     (char*)Vs[w >> 1] + i * 1024);
      }
    }
    __builtin_amdgcn_s_waitcnt(0);
    __syncthreads();

    float p[4][4];
    if (act) {
      const int tk0 = myt * 64;
      floatx4 S[4];
      #pragma unroll
      for (int nt = 0; nt < 4; ++nt) S[nt] = (floatx4){0.f, 0.f, 0.f, 0.f};
      #pragma unroll
      for (int ks = 0; ks < 2; ++ks) {
        bf16x8 a = *(const bf16x8*)(Qs + (wq * 16 + ln15) * 64 + (((ks * 4 + quad) ^ swz)) * 8);
        #pragma unroll
        for (int nt = 0; nt < 4; ++nt) {
          bf16x8 bv = *(const bf16x8*)(&Ks[hh][(nt * 16 + ln15) * 64 + (((ks * 4 + quad) ^ swz)) * 8]);
          S[nt] = __builtin_amdgcn_mfma_f32_16x16x32_bf16(a, bv, S[nt], 0, 0, 0);
        }
      }
      float rmax[4], alpha[4], rsum[4];
      #pragma unroll
      for (int r = 0; r < 4; ++r) rmax[r] = -3e38f;
      #pragma unroll
      for (int nt = 0; nt < 4; ++nt) {
        int col = tk0 + nt * 16 + ln15;
        #pragma unroll
        for (int r = 0; r < 4; ++r) {
          float s = S[nt][r] * 0.125f;
          if (col > qrow + r) s = -3e38f;
          p[nt][r] = s;
          rmax[r] = fmaxf(rmax[r], s);
        }
      }
      #pragma unroll
      for (int r = 0; r < 4; ++r) {
        #pragma unroll
        for (int off = 1; off < 16; off <<= 1)
          rmax[r] = fmaxf(rmax[r], __shfl_xor(rmax[r], off));
        float mn = fmaxf(m_st[r], rmax[r]);
        alpha[r] = __expf(m_st[r] - mn);
        m_st[r] = mn;
        rsum[r] = 0.f;
      }
      #pragma unroll
      for (int nt = 0; nt < 4; ++nt)
        #pragma unroll
        for (int r = 0; r < 4; ++r) {
          float e = __expf(p[nt][r] - m_st[r]);
          p[nt][r] = e;
          rsum[r] += e;
        }
      #pragma unroll
      for (int r = 0; r < 4; ++r) {
        #pragma unroll
        for (int off = 1; off < 16; off <<= 1)
          rsum[r] += __shfl_xor(rsum[r], off);
        l_st[r] = l_st[r] * alpha[r] + rsum[r];
      }
      #pragma unroll
      for (int nt = 0; nt < 4; ++nt)
        #pragma unroll
        for (int r = 0; r < 4; ++r) O[nt][r] *= alpha[r];
      #pragma unroll
      for (int nt = 0; nt < 4; ++nt)
        #pragma unroll
        for (int r = 0; r < 4; ++r)
          Ps[hh][(wq * 16 + quad * 4 + r) * 72 + nt * 16 + ln15] = f2bf(p[nt][r]);
    }
    __syncthreads();
    if (act) {
      #pragma unroll
      for (int ks = 0; ks < 2; ++ks) {
        bf16x8 a = *(const bf16x8*)(&Ps[hh][(wq * 16 + ln15) * 72 + ks * 32 + quad * 8]);
        #pragma unroll
        for (int nt = 0; nt < 4; ++nt) {
          bf16x8 bv = *(const bf16x8*)(&Vs[hh][(nt * 16 + ln15) * 64 + (((ks * 4 + quad) ^ swz)) * 8]);
          O[nt] = __builtin_amdgcn_mfma_f32_16x16x32_bf16(a, bv, O[nt], 0, 0, 0);
        }
      }
    }
  }

  #pragma unroll
  for (int nt = 0; nt < 4; ++nt)
    #pragma unroll
    for (int r = 0; r < 4; ++r)
      Om[hh][wq * 16 + quad * 4 + r][nt * 16 + ln15] = O[nt][r];
  if (ln15 == 0) {
    #pragma unroll
    for (int r = 0; r < 4; ++r) {
      Ml[hh][wq * 16 + quad * 4 + r] = m_st[r];
      Ll[hh][wq * 16 + quad * 4 + r] = l_st[r];
    }
  }
  __syncthreads();

  const int rr = tid >> 3, cg = (tid & 7) * 8;
  float m0 = Ml[0][rr], m1 = Ml[1][rr];
  float l0 = Ll[0][rr], l1 = Ll[1][rr];
  float m = fmaxf(m0, m1);
  float a0 = __expf(m0 - m), a1 = __expf(m1 - m);
  float inv = 1.f / (l0 * a0 + l1 * a1);
  union { u16 s[8]; uint4 v; } o;
  #pragma unroll
  for (int cc = 0; cc < 8; ++cc)
    o.s[cc] = f2bf((Om[0][rr][cg + cc] * a0 + Om[1][rr][cg + cc] * a1) * inv);
  *(uint4*)(o_bh + ((size_t)((b * 8 + h) * 1024 + q0 + rr)) * 64 + cg) = o.v;
}

// ---------------- launch ----------------

extern "C" void kernel_launch(void* const* d_in, const int* in_sizes, int n_in,
                              void* d_out, int out_size, void* d_ws, size_t ws_size,
                              hipStream_t stream) {
  const float* x  = (const float*)d_in[0];
  const float* Wq = (const float*)d_in[1];
  const float* Wk = (const float*)d_in[2];
  const float* Wv = (const float*)d_in[3];
  const float* Ws = (const float*)d_in[4];
  const float* Wd = (const float*)d_in[5];
  const float* Wo = (const float*)d_in[6];
  float* out = (float*)d_out;

  char* ws = (char*)d_ws;
  u16*   WoT  = (u16*)(ws + 0);            //  5,242,880
  u16*   xb   = (u16*)(ws + 5242880);      //  4,194,304
  u16*   WT   = (u16*)(ws + 9437184);      //  7,340,032  (end 16,777,216)
  u16*   c1   = (u16*)(ws + 16777216);     // 14,680,064  (end 31,457,280)
  float* ssg  = (float*)(ws + 31457280);   //    327,680
  u64*   sdb  = (u64*)(ws + 31784960);     //     16,384
  u16*   o_bh = (u16*)(ws + 31801344);     //  2,097,152  (end 33,898,496)
  u16*   vT   = (u16*)(ws + 33898496);     //  2,097,152  (end 35,995,648)
  u16*   Pk   = (u16*)(ws + 35995648);     //  8,388,608  (end 44,384,256)

  preamble_kernel<<<6400, 256, 0, stream>>>(x, Wq, Wk, Wv, Ws, Wd, Wo,
                                            WT, WoT, ssg, sdb, xb);

  // c1 = xb @ WT^T : M=2048, N=3584, K=1024, 128x64 tiles (896 blocks)
  gemm4w_kernel<<<dim3(16, 56), 256, 0, stream>>>(xb, WT, c1, N1, 1024);

  vmix_tr_kernel<<<dim3(16, 32, 2), 256, 0, stream>>>(c1, ssg, vT);

  attn_kernel<<<dim3(32, 16), 256, 0, stream>>>(c1, vT, o_bh);

  // out = (sd ? o : 0) @ WoT^T : 128x64 tiles, split-K=2 (512 blocks)
  gemm2f_kernel<<<dim3(16, 16, 2), 256, 0, stream>>>(o_bh, WoT, sdb, Pk);
  reduce2_kernel<<<1024, 256, 0, stream>>>(Pk, out);
}

// Round 9
// 181.365 us; speedup vs baseline: 1.0028x; 1.0028x over previous
//
#include <hip/hip_runtime.h>

typedef unsigned short u16;
typedef unsigned long long u64;
typedef __bf16 bf16x8 __attribute__((ext_vector_type(8)));
typedef float floatx4 __attribute__((ext_vector_type(4)));

#define B_   2
#define T_   1024
#define DIM_ 1024
#define H_   8
#define DH_  64
#define E_   5

// c1 column layout: [0,512) q | [512,1024) k | [1024,3584) vexp (h,e,dh)
#define N1   3584
#define M_   2048
#define KOUT 2560

__device__ __forceinline__ u16 f2bf(float f) {
  union { float f; unsigned u; } v; v.f = f;
  unsigned r = v.u + 0x7FFFu + ((v.u >> 16) & 1u);
  return (u16)(r >> 16);
}
__device__ __forceinline__ float bf2f(u16 h) {
  union { unsigned u; float f; } v; v.u = ((unsigned)h) << 16;
  return v.f;
}

__device__ __forceinline__ void async_cp16(const void* g, void* l) {
  __builtin_amdgcn_global_load_lds(
      (const __attribute__((address_space(1))) unsigned int*)g,
      (__attribute__((address_space(3))) unsigned int*)l, 16, 0, 0);
}

// ---------------- preamble: [blocks 0..255] logits+topk (+xb emit) | [256..6399] weight prep ----------------
#define XI(r, k) ((r) * 1088 + (k) + (((k) >> 6) << 2))

__global__ __launch_bounds__(256)
void preamble_kernel(const float* __restrict__ x, const float* __restrict__ Wq,
                     const float* __restrict__ Wk, const float* __restrict__ Wv,
                     const float* __restrict__ Ws, const float* __restrict__ Wd,
                     const float* __restrict__ Wo,
                     u16* __restrict__ WT, u16* __restrict__ WoT,
                     float* __restrict__ ssg, u64* __restrict__ sdb,
                     u16* __restrict__ xb) {
  __shared__ __align__(16) char smem[47744];
  const int bx = blockIdx.x;
  const int tid = threadIdx.x;

  if (bx >= 256) {                    // ---- weight prep ----
    const int pb = bx - 256;
    const int kx = pb & 31, nt = pb >> 5;
    if (nt < 112) {
      float (*tile)[33] = (float(*)[33])smem;
      int k0 = kx * 32;
      const float* W; int N, n0, nofs;
      if (nt < 16)      { W = Wq; N = 512;  n0 = nt * 32;        nofs = 0; }
      else if (nt < 32) { W = Wk; N = 512;  n0 = (nt - 16) * 32; nofs = 512; }
      else              { W = Wv; N = 2560; n0 = (nt - 32) * 32; nofs = 1024; }
      int tx = tid & 31, ty = tid >> 5;
      #pragma unroll
      for (int i = 0; i < 32; i += 8)
        tile[ty + i][tx] = W[(size_t)(k0 + ty + i) * N + n0 + tx];
      __syncthreads();
      #pragma unroll
      for (int i = 0; i < 32; i += 8)
        WT[(size_t)(nofs + n0 + ty + i) * 1024 + k0 + tx] = f2bf(tile[tx][ty + i]);
    } else {
      int id = (nt - 112) * 32 + kx;
      int i = id * 256 + tid;
      int c4 = i & 15;
      int t  = i >> 4;
      int d  = t / 40;
      int he = t - d * 40;
      float4 v = *(const float4*)(Wo + ((size_t)(he * 1024 + d) * 64 + c4 * 4));
      union { u16 s[4]; uint2 u; } o;
      o.s[0] = f2bf(v.x); o.s[1] = f2bf(v.y); o.s[2] = f2bf(v.z); o.s[3] = f2bf(v.w);
      *(uint2*)(WoT + (size_t)d * KOUT + he * 64 + c4 * 4) = o.u;
    }
    return;
  }

  // ---- logits + topk, rows bt0..bt0+7 ----
  float* xs = (float*)smem;
  float* ps = xs + 8 * 1088;
  float* lg = ps + 4 * 640;
  unsigned char* mb = (unsigned char*)(lg + 640);
  const int bt0 = bx * 8;

  for (int i = tid; i < 2048; i += 256) {
    int r = i >> 8, j = i & 255;
    float4 v = ((const float4*)(x + (size_t)(bt0 + r) * 1024))[j];
    *(float4*)(xs + XI(r, j * 4)) = v;
    union { u16 h[4]; uint2 u; } o;
    o.h[0] = f2bf(v.x); o.h[1] = f2bf(v.y); o.h[2] = f2bf(v.z); o.h[3] = f2bf(v.w);
    *(uint2*)(xb + (size_t)(bt0 + r) * 1024 + j * 4) = o.u;
  }
  __syncthreads();

  const int cx = tid & 15;
  const int ky = tid >> 4;
  float acc[8][5];
  #pragma unroll
  for (int r = 0; r < 8; ++r)
    #pragma unroll
    for (int c = 0; c < 5; ++c) acc[r][c] = 0.f;

  for (int q4 = 0; q4 < 16; ++q4) {
    const int k = ky * 64 + q4 * 4;
    float4 xr[8];
    #pragma unroll
    for (int r = 0; r < 8; ++r) xr[r] = *(const float4*)(xs + XI(r, k));
    #pragma unroll
    for (int c = 0; c < 5; ++c) {
      const int col = cx * 5 + c;
      const float* Wp = (col < 40) ? (Ws + col) : (Wd + col - 40);
      float w0 = Wp[(size_t)(k + 0) * 40], w1 = Wp[(size_t)(k + 1) * 40];
      float w2 = Wp[(size_t)(k + 2) * 40], w3 = Wp[(size_t)(k + 3) * 40];
      #pragma unroll
      for (int r = 0; r < 8; ++r) {
        float a = acc[r][c];
        a = fmaf(xr[r].x, w0, a); a = fmaf(xr[r].y, w1, a);
        a = fmaf(xr[r].z, w2, a); a = fmaf(xr[r].w, w3, a);
        acc[r][c] = a;
      }
    }
  }

  #pragma unroll
  for (int r = 0; r < 8; ++r)
    #pragma unroll
    for (int c = 0; c < 5; ++c) {
      float a = acc[r][c];
      a += __shfl_xor(a, 16);
      a += __shfl_xor(a, 32);
      acc[r][c] = a;
    }
  const int w = tid >> 6, lane = tid & 63;
  if (lane < 16) {
    #pragma unroll
    for (int r = 0; r < 8; ++r)
      #pragma unroll
      for (int c = 0; c < 5; ++c)
        ps[w * 640 + r * 80 + lane * 5 + c] = acc[r][c];
  }
  __syncthreads();
  for (int idx = tid; idx < 640; idx += 256)
    lg[idx] = ps[idx] + ps[640 + idx] + ps[1280 + idx] + ps[1920 + idx];
  __syncthreads();

  if (tid < 128) {
    const int r = tid >> 4, h = (tid >> 1) & 7, side = tid & 1;
    float z[E_], g[E_]; bool sel[E_];
    #pragma unroll
    for (int e = 0; e < E_; ++e) {
      z[e] = lg[r * 80 + side * 40 + h * E_ + e];
      g[e] = 1.f / (1.f + __expf(-z[e]));
      sel[e] = false;
    }
    #pragma unroll
    for (int it = 0; it < 3; ++it) {
      int bi = 0; float bv = -3e38f;
      #pragma unroll
      for (int e = 0; e < E_; ++e)
        if (!sel[e] && z[e] > bv) { bv = z[e]; bi = e; }
      sel[bi] = true;
    }
    if (side == 0) {
      #pragma unroll
      for (int e = 0; e < E_; ++e)
        ssg[(size_t)(bt0 + r) * 40 + h * E_ + e] = sel[e] ? g[e] : 0.f;
    } else {
      unsigned bits = 0;
      #pragma unroll
      for (int e = 0; e < E_; ++e) bits |= (sel[e] ? 1u : 0u) << e;
      mb[r * 8 + h] = (unsigned char)bits;
    }
  }
  __syncthreads();
  if (tid < 8) {
    u64 m = 0;
    #pragma unroll
    for (int hh = 0; hh < 8; ++hh) m |= (u64)mb[tid * 8 + hh] << (5 * hh);
    sdb[bt0 + tid] = m;
  }
}

// ---------------- MFMA GEMM, 128x128 tile, BK=64, swizzled LDS, coalesced epilogue ----------------

__global__ __launch_bounds__(256, 2)
void gemm4w_kernel(const u16* __restrict__ A, const u16* __restrict__ Bm,
                   u16* __restrict__ C, int N, int Kd) {
  __shared__ __align__(16) u16 As[128 * 64];   // 16 KB
  __shared__ __align__(16) u16 Bs[128 * 64];   // 16 KB
  const int tid = threadIdx.x;
  const int w = tid >> 6, lane = tid & 63;
  const int ln15 = lane & 15, quad = lane >> 4;
  const int wm = w >> 1, wn = w & 1;
  const int bm0 = blockIdx.x * 128, bn0 = blockIdx.y * 128;
  const int r8 = lane >> 3;
  const int g8 = ((lane & 7) ^ r8) * 8;
  const int swz = ln15 & 7;

  floatx4 acc[4][4];
  #pragma unroll
  for (int i = 0; i < 4; ++i)
    #pragma unroll
    for (int j = 0; j < 4; ++j) acc[i][j] = (floatx4){0.f, 0.f, 0.f, 0.f};

  for (int k0 = 0; k0 < Kd; k0 += 64) {
    __syncthreads();
    #pragma unroll
    for (int j = 0; j < 4; ++j) {
      int i = w * 4 + j;
      async_cp16(A + (size_t)(bm0 + i * 8 + r8) * Kd + k0 + g8, (char*)As + i * 1024);
      async_cp16(Bm + (size_t)(bn0 + i * 8 + r8) * Kd + k0 + g8, (char*)Bs + i * 1024);
    }
    __builtin_amdgcn_s_waitcnt(0);
    __syncthreads();

    #pragma unroll
    for (int t = 0; t < 2; ++t) {
      bf16x8 af[4], bf[4];
      #pragma unroll
      for (int mt = 0; mt < 4; ++mt)
        af[mt] = *(const bf16x8*)(As + (wm * 64 + mt * 16 + ln15) * 64 + (((t * 4 + quad) ^ swz) * 8));
      #pragma unroll
      for (int nt = 0; nt < 4; ++nt)
        bf[nt] = *(const bf16x8*)(Bs + (wn * 64 + nt * 16 + ln15) * 64 + (((t * 4 + quad) ^ swz) * 8));
      #pragma unroll
      for (int mt = 0; mt < 4; ++mt)
        #pragma unroll
        for (int nt = 0; nt < 4; ++nt)
          acc[mt][nt] = __builtin_amdgcn_mfma_f32_16x16x32_bf16(af[mt], bf[nt], acc[mt][nt], 0, 0, 0);
    }
  }

  // coalesced epilogue: acc -> bf16 in LDS (8 KB/wave) -> b128 stores (128-B segments)
  __syncthreads();
  {
    u16* myt = ((w < 2) ? As : Bs) + (w & 1) * 4096;
    #pragma unroll
    for (int mt = 0; mt < 4; ++mt)
      #pragma unroll
      for (int nt = 0; nt < 4; ++nt)
        #pragma unroll
        for (int r = 0; r < 4; ++r)
          myt[(mt * 16 + quad * 4 + r) * 64 + nt * 16 + ln15] = f2bf(acc[mt][nt][r]);
  }
  __syncthreads();
  #pragma unroll
  for (int p = 0; p < 8; ++p) {
    int rr = p * 16 + (tid >> 4);
    int cc = tid & 15;
    int wv = ((rr >> 6) << 1) | (cc >> 3);          // source wave tile
    const u16* src = ((wv < 2) ? As : Bs) + (wv & 1) * 4096 + (rr & 63) * 64 + (cc & 7) * 8;
    uint4 val = *(const uint4*)src;
    *(uint4*)(C + (size_t)(bm0 + rr) * N + bn0 + cc * 8) = val;
  }
}

// ---------------- GEMM2 fused: 128x128, SK=4, sd-gated A, coalesced epilogue ----------------

__global__ __launch_bounds__(256, 2)
void gemm2f_kernel(const u16* __restrict__ o_bh, const u16* __restrict__ WoT,
                   const u64* __restrict__ sdb, u16* __restrict__ Pk) {
  __shared__ __align__(16) u16 As[128 * 64];
  __shared__ __align__(16) u16 Bs[128 * 64];
  const int tid = threadIdx.x;
  const int w = tid >> 6, lane = tid & 63;
  const int ln15 = lane & 15, quad = lane >> 4;
  const int wm = w >> 1, wn = w & 1;
  const int bm0 = blockIdx.x * 128, bn0 = blockIdx.y * 128;
  const int b = bm0 >> 10;
  const int t_base = bm0 & 1023;
  const int r8 = lane >> 3;
  const int g8 = ((lane & 7) ^ r8) * 8;
  const int swz = ln15 & 7;
  const int kbeg = blockIdx.z * 640;

  u64 sdr[4];
  #pragma unroll
  for (int mt = 0; mt < 4; ++mt)
    sdr[mt] = sdb[bm0 + wm * 64 + mt * 16 + ln15];

  floatx4 acc[4][4];
  #pragma unroll
  for (int i = 0; i < 4; ++i)
    #pragma unroll
    for (int j = 0; j < 4; ++j) acc[i][j] = (floatx4){0.f, 0.f, 0.f, 0.f};

  for (int k0 = kbeg; k0 < kbeg + 640; k0 += 64) {
    const int he = k0 >> 6;
    const int h = (he * 205) >> 10;              // he / 5
    const u16* abase = o_bh + (size_t)((b * 8 + h) * 1024 + t_base) * 64;
    __syncthreads();
    #pragma unroll
    for (int j = 0; j < 4; ++j) {
      int i = w * 4 + j;
      async_cp16(abase + (size_t)(i * 8 + r8) * 64 + g8, (char*)As + i * 1024);
      async_cp16(WoT + (size_t)(bn0 + i * 8 + r8) * KOUT + k0 + g8, (char*)Bs + i * 1024);
    }
    __builtin_amdgcn_s_waitcnt(0);
    __syncthreads();

    union { uint4 u; bf16x8 v; } z8; z8.u = (uint4){0u, 0u, 0u, 0u};
    #pragma unroll
    for (int t = 0; t < 2; ++t) {
      bf16x8 af[4], bf[4];
      #pragma unroll
      for (int mt = 0; mt < 4; ++mt) {
        af[mt] = *(const bf16x8*)(As + (wm * 64 + mt * 16 + ln15) * 64 + (((t * 4 + quad) ^ swz) * 8));
        if (!((sdr[mt] >> he) & 1)) af[mt] = z8.v;
      }
      #pragma unroll
      for (int nt = 0; nt < 4; ++nt)
        bf[nt] = *(const bf16x8*)(Bs + (wn * 64 + nt * 16 + ln15) * 64 + (((t * 4 + quad) ^ swz) * 8));
      #pragma unroll
      for (int mt = 0; mt < 4; ++mt)
        #pragma unroll
        for (int nt = 0; nt < 4; ++nt)
          acc[mt][nt] = __builtin_amdgcn_mfma_f32_16x16x32_bf16(af[mt], bf[nt], acc[mt][nt], 0, 0, 0);
    }
  }

  __syncthreads();
  {
    u16* myt = ((w < 2) ? As : Bs) + (w & 1) * 4096;
    #pragma unroll
    for (int mt = 0; mt < 4; ++mt)
      #pragma unroll
      for (int nt = 0; nt < 4; ++nt)
        #pragma unroll
        for (int r = 0; r < 4; ++r)
          myt[(mt * 16 + quad * 4 + r) * 64 + nt * 16 + ln15] = f2bf(acc[mt][nt][r]);
  }
  __syncthreads();
  u16* Cz = Pk + (size_t)blockIdx.z * M_ * 1024;
  #pragma unroll
  for (int p = 0; p < 8; ++p) {
    int rr = p * 16 + (tid >> 4);
    int cc = tid & 15;
    int wv = ((rr >> 6) << 1) | (cc >> 3);
    const u16* src = ((wv < 2) ? As : Bs) + (wv & 1) * 4096 + (rr & 63) * 64 + (cc & 7) * 8;
    uint4 val = *(const uint4*)src;
    *(uint4*)(Cz + (size_t)(bm0 + rr) * 1024 + bn0 + cc * 8) = val;
  }
}

// reduce 4 bf16 split-K partials -> fp32 out
__global__ void reduce4_kernel(const u16* __restrict__ Pk, float* __restrict__ out) {
  int i = blockIdx.x * 256 + threadIdx.x;
  size_t base = (size_t)i * 8;
  float s[8] = {0.f, 0.f, 0.f, 0.f, 0.f, 0.f, 0.f, 0.f};
  #pragma unroll
  for (int z = 0; z < 4; ++z) {
    union { uint4 v; u16 h[8]; } u;
    u.v = *(const uint4*)(Pk + (size_t)z * M_ * 1024 + base);
    #pragma unroll
    for (int c = 0; c < 8; ++c) s[c] += bf2f(u.h[c]);
  }
  float4 o0 = {s[0], s[1], s[2], s[3]}, o1 = {s[4], s[5], s[6], s[7]};
  *(float4*)(out + base) = o0;
  *(float4*)(out + base + 4) = o1;
}

// ---------------- fused V-mix + transpose ----------------

__global__ __launch_bounds__(256)
void vmix_tr_kernel(const u16* __restrict__ c1, const float* __restrict__ ssg,
                    u16* __restrict__ vT) {
  __shared__ u16 tile[32][33];
  const int bh = blockIdx.x;
  const int b = bh >> 3, h = bh & 7;
  const int t0 = blockIdx.y * 32, d0 = blockIdx.z * 32;
  const int dh = threadIdx.x & 31, tl = threadIdx.x >> 5;
  #pragma unroll
  for (int i = 0; i < 4; ++i) {
    int trow = tl + i * 8;
    size_t bt = (size_t)b * T_ + t0 + trow;
    const u16* ve = c1 + bt * N1 + 1024 + h * (E_ * 64) + d0 + dh;
    const float* g = ssg + bt * 40 + h * E_;
    float s = 0.f;
    #pragma unroll
    for (int e = 0; e < E_; ++e) s = fmaf(g[e], bf2f(ve[e * 64]), s);
    tile[trow][dh] = f2bf(s);
  }
  __syncthreads();
  #pragma unroll
  for (int i = 0; i < 4; ++i) {
    int d = d0 + tl + i * 8;
    vT[((size_t)(b * H_ + h) * DH_ + d) * T_ + t0 + dh] = tile[dh][tl + i * 8];
  }
}

// ---------------- flash attention: balanced 32-row Q tiles, wave-pairs split kt ----------------

__global__ __launch_bounds__(256)
void attn_kernel(const u16* __restrict__ c1, const u16* __restrict__ vT,
                 u16* __restrict__ o_bh) {
  __shared__ __align__(16) u16 Qs[32 * 64];
  __shared__ __align__(16) u16 Ks[2][64 * 64];
  __shared__ __align__(16) u16 Vs[2][64 * 64];
  __shared__ __align__(16) u16 Ps[2][32 * 72];
  __shared__ float Om[2][32][68];
  __shared__ float Ml[2][32], Ll[2][32];
  const int bx = blockIdx.x;
  const int qi = (bx & 1) ? (bx >> 1) : (31 - (bx >> 1));
  const int bh = blockIdx.y;
  const int b = bh >> 3, h = bh & 7;
  const int tid = threadIdx.x;
  const int w = tid >> 6, lane = tid & 63;
  const int ln15 = lane & 15, quad = lane >> 4;
  const int hh = w >> 1, wq = w & 1;
  const int q0 = qi * 32;
  const int nkt = (qi >> 1) + 1;
  const int h0n = (nkt + 1) >> 1;
  const int r8 = lane >> 3;
  const int g8 = ((lane & 7) ^ ((lane >> 3) & 7)) * 8;
  const int swz = ln15 & 7;

  async_cp16(c1 + (size_t)(b * T_ + q0 + w * 8 + r8) * N1 + h * DH_ + g8,
             (char*)Qs + w * 1024);

  floatx4 O[4];
  float m_st[4], l_st[4];
  #pragma unroll
  for (int j = 0; j < 4; ++j) {
    O[j] = (floatx4){0.f, 0.f, 0.f, 0.f};
    m_st[j] = -3e38f; l_st[j] = 0.f;
  }
  const int qrow = q0 + wq * 16 + quad * 4;

  for (int j = 0; j < h0n; ++j) {
    const int myt = hh ? (h0n + j) : j;
    const bool act = (hh == 0) || (h0n + j < nkt);
    __syncthreads();
    if (w < 2 || h0n + j < nkt) {
      const int tk = (w < 2 ? j : h0n + j) * 64;
      if ((w & 1) == 0) {
        #pragma unroll
        for (int i = 0; i < 8; ++i)
          async_cp16(c1 + (size_t)(b * T_ + tk + i * 8 + r8) * N1 + 512 + h * DH_ + g8,
                     (char*)Ks[w >> 1] + i * 1024);
      } else {
        #pragma unroll
        for (int i = 0; i < 8; ++i)
          async_cp16(vT + (size_t)((b * H_ + h) * DH_ + i * 8 + r8) * T_ + tk + g8,
                     (char*)Vs[w >> 1] + i * 1024);
      }
    }
    __builtin_amdgcn_s_waitcnt(0);
    __syncthreads();

    float p[4][4];
    if (act) {
      const int tk0 = myt * 64;
      floatx4 S[4];
      #pragma unroll
      for (int nt = 0; nt < 4; ++nt) S[nt] = (floatx4){0.f, 0.f, 0.f, 0.f};
      #pragma unroll
      for (int ks = 0; ks < 2; ++ks) {
        bf16x8 a = *(const bf16x8*)(Qs + (wq * 16 + ln15) * 64 + (((ks * 4 + quad) ^ swz)) * 8);
        #pragma unroll
        for (int nt = 0; nt < 4; ++nt) {
          bf16x8 bv = *(const bf16x8*)(&Ks[hh][(nt * 16 + ln15) * 64 + (((ks * 4 + quad) ^ swz)) * 8]);
          S[nt] = __builtin_amdgcn_mfma_f32_16x16x32_bf16(a, bv, S[nt], 0, 0, 0);
        }
      }
      float rmax[4], alpha[4], rsum[4];
      #pragma unroll
      for (int r = 0; r < 4; ++r) rmax[r] = -3e38f;
      #pragma unroll
      for (int nt = 0; nt < 4; ++nt) {
        int col = tk0 + nt * 16 + ln15;
        #pragma unroll
        for (int r = 0; r < 4; ++r) {
          float s = S[nt][r] * 0.125f;
          if (col > qrow + r) s = -3e38f;
          p[nt][r] = s;
          rmax[r] = fmaxf(rmax[r], s);
        }
      }
      #pragma unroll
      for (int r = 0; r < 4; ++r) {
        #pragma unroll
        for (int off = 1; off < 16; off <<= 1)
          rmax[r] = fmaxf(rmax[r], __shfl_xor(rmax[r], off));
        float mn = fmaxf(m_st[r], rmax[r]);
        alpha[r] = __expf(m_st[r] - mn);
        m_st[r] = mn;
        rsum[r] = 0.f;
      }
      #pragma unroll
      for (int nt = 0; nt < 4; ++nt)
        #pragma unroll
        for (int r = 0; r < 4; ++r) {
          float e = __expf(p[nt][r] - m_st[r]);
          p[nt][r] = e;
          rsum[r] += e;
        }
      #pragma unroll
      for (int r = 0; r < 4; ++r) {
        #pragma unroll
        for (int off = 1; off < 16; off <<= 1)
          rsum[r] += __shfl_xor(rsum[r], off);
        l_st[r] = l_st[r] * alpha[r] + rsum[r];
      }
      #pragma unroll
      for (int nt = 0; nt < 4; ++nt)
        #pragma unroll
        for (int r = 0; r < 4; ++r) O[nt][r] *= alpha[r];
      #pragma unroll
      for (int nt = 0; nt < 4; ++nt)
        #pragma unroll
        for (int r = 0; r < 4; ++r)
          Ps[hh][(wq * 16 + quad * 4 + r) * 72 + nt * 16 + ln15] = f2bf(p[nt][r]);
    }
    __syncthreads();
    if (act) {
      #pragma unroll
      for (int ks = 0; ks < 2; ++ks) {
        bf16x8 a = *(const bf16x8*)(&Ps[hh][(wq * 16 + ln15) * 72 + ks * 32 + quad * 8]);
        #pragma unroll
        for (int nt = 0; nt < 4; ++nt) {
          bf16x8 bv = *(const bf16x8*)(&Vs[hh][(nt * 16 + ln15) * 64 + (((ks * 4 + quad) ^ swz)) * 8]);
          O[nt] = __builtin_amdgcn_mfma_f32_16x16x32_bf16(a, bv, O[nt], 0, 0, 0);
        }
      }
    }
  }

  #pragma unroll
  for (int nt = 0; nt < 4; ++nt)
    #pragma unroll
    for (int r = 0; r < 4; ++r)
      Om[hh][wq * 16 + quad * 4 + r][nt * 16 + ln15] = O[nt][r];
  if (ln15 == 0) {
    #pragma unroll
    for (int r = 0; r < 4; ++r) {
      Ml[hh][wq * 16 + quad * 4 + r] = m_st[r];
      Ll[hh][wq * 16 + quad * 4 + r] = l_st[r];
    }
  }
  __syncthreads();

  const int rr = tid >> 3, cg = (tid & 7) * 8;
  float m0 = Ml[0][rr], m1 = Ml[1][rr];
  float l0 = Ll[0][rr], l1 = Ll[1][rr];
  float m = fmaxf(m0, m1);
  float a0 = __expf(m0 - m), a1 = __expf(m1 - m);
  float inv = 1.f / (l0 * a0 + l1 * a1);
  union { u16 s[8]; uint4 v; } o;
  #pragma unroll
  for (int cc = 0; cc < 8; ++cc)
    o.s[cc] = f2bf((Om[0][rr][cg + cc] * a0 + Om[1][rr][cg + cc] * a1) * inv);
  *(uint4*)(o_bh + ((size_t)((b * 8 + h) * 1024 + q0 + rr)) * 64 + cg) = o.v;
}

// ---------------- launch ----------------

extern "C" void kernel_launch(void* const* d_in, const int* in_sizes, int n_in,
                              void* d_out, int out_size, void* d_ws, size_t ws_size,
                              hipStream_t stream) {
  const float* x  = (const float*)d_in[0];
  const float* Wq = (const float*)d_in[1];
  const float* Wk = (const float*)d_in[2];
  const float* Wv = (const float*)d_in[3];
  const float* Ws = (const float*)d_in[4];
  const float* Wd = (const float*)d_in[5];
  const float* Wo = (const float*)d_in[6];
  float* out = (float*)d_out;

  char* ws = (char*)d_ws;
  u16*   WoT  = (u16*)(ws + 0);            //  5,242,880
  u16*   xb   = (u16*)(ws + 5242880);      //  4,194,304
  u16*   WT   = (u16*)(ws + 9437184);      //  7,340,032  (end 16,777,216)
  u16*   c1   = (u16*)(ws + 16777216);     // 14,680,064  (end 31,457,280)
  float* ssg  = (float*)(ws + 31457280);   //    327,680
  u64*   sdb  = (u64*)(ws + 31784960);     //     16,384
  u16*   o_bh = (u16*)(ws + 31801344);     //  2,097,152  (end 33,898,496)
  u16*   vT   = (u16*)(ws + 33898496);     //  2,097,152  (end 35,995,648)
  u16*   Pk   = (u16*)(ws + 35995648);     // 16,777,216  (end 52,772,864)

  preamble_kernel<<<6400, 256, 0, stream>>>(x, Wq, Wk, Wv, Ws, Wd, Wo,
                                            WT, WoT, ssg, sdb, xb);

  // c1 = xb @ WT^T : M=2048, N=3584, K=1024, BK=64 (448 blocks)
  gemm4w_kernel<<<dim3(16, 28), 256, 0, stream>>>(xb, WT, c1, N1, 1024);

  vmix_tr_kernel<<<dim3(16, 32, 2), 256, 0, stream>>>(c1, ssg, vT);

  attn_kernel<<<dim3(32, 16), 256, 0, stream>>>(c1, vT, o_bh);

  // out = (sd ? o : 0) @ WoT^T : 128x128, split-K=4 (512 blocks)
  gemm2f_kernel<<<dim3(16, 8, 4), 256, 0, stream>>>(o_bh, WoT, sdb, Pk);
  reduce4_kernel<<<1024, 256, 0, stream>>>(Pk, out);
}

// Round 10
// 179.481 us; speedup vs baseline: 1.0133x; 1.0105x over previous
//
#include <hip/hip_runtime.h>

typedef unsigned short u16;
typedef unsigned long long u64;
typedef __bf16 bf16x8 __attribute__((ext_vector_type(8)));
typedef float floatx4 __attribute__((ext_vector_type(4)));

#define B_   2
#define T_   1024
#define DIM_ 1024
#define H_   8
#define DH_  64
#define E_   5

// c1 column layout: [0,512) q | [512,1024) k | [1024,3584) vexp (h,e,dh)
#define N1   3584
#define M_   2048
#define KOUT 2560

__device__ __forceinline__ u16 f2bf(float f) {
  union { float f; unsigned u; } v; v.f = f;
  unsigned r = v.u + 0x7FFFu + ((v.u >> 16) & 1u);
  return (u16)(r >> 16);
}
__device__ __forceinline__ float bf2f(u16 h) {
  union { unsigned u; float f; } v; v.u = ((unsigned)h) << 16;
  return v.f;
}

__device__ __forceinline__ void async_cp16(const void* g, void* l) {
  __builtin_amdgcn_global_load_lds(
      (const __attribute__((address_space(1))) unsigned int*)g,
      (__attribute__((address_space(3))) unsigned int*)l, 16, 0, 0);
}

// ---------------- preamble: [blocks 0..255] logits+topk (+xb emit) | [256..6399] weight prep ----------------
#define XI(r, k) ((r) * 1088 + (k) + (((k) >> 6) << 2))

__global__ __launch_bounds__(256)
void preamble_kernel(const float* __restrict__ x, const float* __restrict__ Wq,
                     const float* __restrict__ Wk, const float* __restrict__ Wv,
                     const float* __restrict__ Ws, const float* __restrict__ Wd,
                     const float* __restrict__ Wo,
                     u16* __restrict__ WT, u16* __restrict__ WoT,
                     float* __restrict__ ssg, u64* __restrict__ sdb,
                     u16* __restrict__ xb) {
  __shared__ __align__(16) char smem[47744];
  const int bx = blockIdx.x;
  const int tid = threadIdx.x;

  if (bx >= 256) {                    // ---- weight prep ----
    const int pb = bx - 256;
    const int kx = pb & 31, nt = pb >> 5;
    if (nt < 112) {
      float (*tile)[33] = (float(*)[33])smem;
      int k0 = kx * 32;
      const float* W; int N, n0, nofs;
      if (nt < 16)      { W = Wq; N = 512;  n0 = nt * 32;        nofs = 0; }
      else if (nt < 32) { W = Wk; N = 512;  n0 = (nt - 16) * 32; nofs = 512; }
      else              { W = Wv; N = 2560; n0 = (nt - 32) * 32; nofs = 1024; }
      int tx = tid & 31, ty = tid >> 5;
      #pragma unroll
      for (int i = 0; i < 32; i += 8)
        tile[ty + i][tx] = W[(size_t)(k0 + ty + i) * N + n0 + tx];
      __syncthreads();
      #pragma unroll
      for (int i = 0; i < 32; i += 8)
        WT[(size_t)(nofs + n0 + ty + i) * 1024 + k0 + tx] = f2bf(tile[tx][ty + i]);
    } else {
      int id = (nt - 112) * 32 + kx;
      int i = id * 256 + tid;
      int c4 = i & 15;
      int t  = i >> 4;
      int d  = t / 40;
      int he = t - d * 40;
      float4 v = *(const float4*)(Wo + ((size_t)(he * 1024 + d) * 64 + c4 * 4));
      union { u16 s[4]; uint2 u; } o;
      o.s[0] = f2bf(v.x); o.s[1] = f2bf(v.y); o.s[2] = f2bf(v.z); o.s[3] = f2bf(v.w);
      *(uint2*)(WoT + (size_t)d * KOUT + he * 64 + c4 * 4) = o.u;
    }
    return;
  }

  // ---- logits + topk, rows bt0..bt0+7 ----
  float* xs = (float*)smem;
  float* ps = xs + 8 * 1088;
  float* lg = ps + 4 * 640;
  unsigned char* mb = (unsigned char*)(lg + 640);
  const int bt0 = bx * 8;

  for (int i = tid; i < 2048; i += 256) {
    int r = i >> 8, j = i & 255;
    float4 v = ((const float4*)(x + (size_t)(bt0 + r) * 1024))[j];
    *(float4*)(xs + XI(r, j * 4)) = v;
    union { u16 h[4]; uint2 u; } o;
    o.h[0] = f2bf(v.x); o.h[1] = f2bf(v.y); o.h[2] = f2bf(v.z); o.h[3] = f2bf(v.w);
    *(uint2*)(xb + (size_t)(bt0 + r) * 1024 + j * 4) = o.u;
  }
  __syncthreads();

  const int cx = tid & 15;
  const int ky = tid >> 4;
  float acc[8][5];
  #pragma unroll
  for (int r = 0; r < 8; ++r)
    #pragma unroll
    for (int c = 0; c < 5; ++c) acc[r][c] = 0.f;

  for (int q4 = 0; q4 < 16; ++q4) {
    const int k = ky * 64 + q4 * 4;
    float4 xr[8];
    #pragma unroll
    for (int r = 0; r < 8; ++r) xr[r] = *(const float4*)(xs + XI(r, k));
    #pragma unroll
    for (int c = 0; c < 5; ++c) {
      const int col = cx * 5 + c;
      const float* Wp = (col < 40) ? (Ws + col) : (Wd + col - 40);
      float w0 = Wp[(size_t)(k + 0) * 40], w1 = Wp[(size_t)(k + 1) * 40];
      float w2 = Wp[(size_t)(k + 2) * 40], w3 = Wp[(size_t)(k + 3) * 40];
      #pragma unroll
      for (int r = 0; r < 8; ++r) {
        float a = acc[r][c];
        a = fmaf(xr[r].x, w0, a); a = fmaf(xr[r].y, w1, a);
        a = fmaf(xr[r].z, w2, a); a = fmaf(xr[r].w, w3, a);
        acc[r][c] = a;
      }
    }
  }

  #pragma unroll
  for (int r = 0; r < 8; ++r)
    #pragma unroll
    for (int c = 0; c < 5; ++c) {
      float a = acc[r][c];
      a += __shfl_xor(a, 16);
      a += __shfl_xor(a, 32);
      acc[r][c] = a;
    }
  const int w = tid >> 6, lane = tid & 63;
  if (lane < 16) {
    #pragma unroll
    for (int r = 0; r < 8; ++r)
      #pragma unroll
      for (int c = 0; c < 5; ++c)
        ps[w * 640 + r * 80 + lane * 5 + c] = acc[r][c];
  }
  __syncthreads();
  for (int idx = tid; idx < 640; idx += 256)
    lg[idx] = ps[idx] + ps[640 + idx] + ps[1280 + idx] + ps[1920 + idx];
  __syncthreads();

  if (tid < 128) {
    const int r = tid >> 4, h = (tid >> 1) & 7, side = tid & 1;
    float z[E_], g[E_]; bool sel[E_];
    #pragma unroll
    for (int e = 0; e < E_; ++e) {
      z[e] = lg[r * 80 + side * 40 + h * E_ + e];
      g[e] = 1.f / (1.f + __expf(-z[e]));
      sel[e] = false;
    }
    #pragma unroll
    for (int it = 0; it < 3; ++it) {
      int bi = 0; float bv = -3e38f;
      #pragma unroll
      for (int e = 0; e < E_; ++e)
        if (!sel[e] && z[e] > bv) { bv = z[e]; bi = e; }
      sel[bi] = true;
    }
    if (side == 0) {
      #pragma unroll
      for (int e = 0; e < E_; ++e)
        ssg[(size_t)(bt0 + r) * 40 + h * E_ + e] = sel[e] ? g[e] : 0.f;
    } else {
      unsigned bits = 0;
      #pragma unroll
      for (int e = 0; e < E_; ++e) bits |= (sel[e] ? 1u : 0u) << e;
      mb[r * 8 + h] = (unsigned char)bits;
    }
  }
  __syncthreads();
  if (tid < 8) {
    u64 m = 0;
    #pragma unroll
    for (int hh = 0; hh < 8; ++hh) m |= (u64)mb[tid * 8 + hh] << (5 * hh);
    sdb[bt0 + tid] = m;
  }
}

// ---------------- MFMA GEMM, 128x128 tile, BK=64, swizzled LDS, C = A @ B^T ----------------

__global__ __launch_bounds__(256, 2)
void gemm4w_kernel(const u16* __restrict__ A, const u16* __restrict__ Bm,
                   u16* __restrict__ C, int N, int Kd) {
  __shared__ __align__(16) u16 As[128 * 64];   // 16 KB
  __shared__ __align__(16) u16 Bs[128 * 64];   // 16 KB
  const int tid = threadIdx.x;
  const int w = tid >> 6, lane = tid & 63;
  const int ln15 = lane & 15, quad = lane >> 4;
  const int wm = w >> 1, wn = w & 1;
  const int bm0 = blockIdx.x * 128, bn0 = blockIdx.y * 128;
  const int r8 = lane >> 3;
  const int g8 = ((lane & 7) ^ r8) * 8;        // swizzled src chunk
  const int swz = ln15 & 7;

  floatx4 acc[4][4];
  #pragma unroll
  for (int i = 0; i < 4; ++i)
    #pragma unroll
    for (int j = 0; j < 4; ++j) acc[i][j] = (floatx4){0.f, 0.f, 0.f, 0.f};

  for (int k0 = 0; k0 < Kd; k0 += 64) {
    __syncthreads();
    #pragma unroll
    for (int j = 0; j < 4; ++j) {
      int i = w * 4 + j;                        // 8-row groups
      async_cp16(A + (size_t)(bm0 + i * 8 + r8) * Kd + k0 + g8, (char*)As + i * 1024);
      async_cp16(Bm + (size_t)(bn0 + i * 8 + r8) * Kd + k0 + g8, (char*)Bs + i * 1024);
    }
    __builtin_amdgcn_s_waitcnt(0);
    __syncthreads();

    #pragma unroll
    for (int t = 0; t < 2; ++t) {
      bf16x8 af[4], bf[4];
      #pragma unroll
      for (int mt = 0; mt < 4; ++mt)
        af[mt] = *(const bf16x8*)(As + (wm * 64 + mt * 16 + ln15) * 64 + (((t * 4 + quad) ^ swz) * 8));
      #pragma unroll
      for (int nt = 0; nt < 4; ++nt)
        bf[nt] = *(const bf16x8*)(Bs + (wn * 64 + nt * 16 + ln15) * 64 + (((t * 4 + quad) ^ swz) * 8));
      #pragma unroll
      for (int mt = 0; mt < 4; ++mt)
        #pragma unroll
        for (int nt = 0; nt < 4; ++nt)
          acc[mt][nt] = __builtin_amdgcn_mfma_f32_16x16x32_bf16(af[mt], bf[nt], acc[mt][nt], 0, 0, 0);
    }
  }

  #pragma unroll
  for (int mt = 0; mt < 4; ++mt)
    #pragma unroll
    for (int nt = 0; nt < 4; ++nt)
      #pragma unroll
      for (int r = 0; r < 4; ++r) {
        int m = bm0 + wm * 64 + mt * 16 + quad * 4 + r;
        int n = bn0 + wn * 64 + nt * 16 + ln15;
        C[(size_t)m * N + n] = f2bf(acc[mt][nt][r]);
      }
}

// ---------------- GEMM2 fused: A[bt][he*64+c] = (sdb>>he&1) ? o_bh[b,h,t,c] : 0 ----------------

__global__ __launch_bounds__(256, 2)
void gemm2f_kernel(const u16* __restrict__ o_bh, const u16* __restrict__ WoT,
                   const u64* __restrict__ sdb, u16* __restrict__ Pk) {
  __shared__ __align__(16) u16 As[128 * 64];
  __shared__ __align__(16) u16 Bs[128 * 64];
  const int tid = threadIdx.x;
  const int w = tid >> 6, lane = tid & 63;
  const int ln15 = lane & 15, quad = lane >> 4;
  const int wm = w >> 1, wn = w & 1;
  const int bm0 = blockIdx.x * 128, bn0 = blockIdx.y * 128;
  const int b = bm0 >> 10;
  const int t_base = bm0 & 1023;
  const int r8 = lane >> 3;
  const int g8 = ((lane & 7) ^ r8) * 8;
  const int swz = ln15 & 7;
  const int kbeg = blockIdx.z * 640;

  u64 sdr[4];
  #pragma unroll
  for (int mt = 0; mt < 4; ++mt)
    sdr[mt] = sdb[bm0 + wm * 64 + mt * 16 + ln15];

  floatx4 acc[4][4];
  #pragma unroll
  for (int i = 0; i < 4; ++i)
    #pragma unroll
    for (int j = 0; j < 4; ++j) acc[i][j] = (floatx4){0.f, 0.f, 0.f, 0.f};

  for (int k0 = kbeg; k0 < kbeg + 640; k0 += 64) {
    const int he = k0 >> 6;                      // one head-channel block per iter
    const int h = (he * 205) >> 10;              // he / 5
    const u16* abase = o_bh + (size_t)((b * 8 + h) * 1024 + t_base) * 64;
    __syncthreads();
    #pragma unroll
    for (int j = 0; j < 4; ++j) {
      int i = w * 4 + j;
      async_cp16(abase + (size_t)(i * 8 + r8) * 64 + g8, (char*)As + i * 1024);
      async_cp16(WoT + (size_t)(bn0 + i * 8 + r8) * KOUT + k0 + g8, (char*)Bs + i * 1024);
    }
    __builtin_amdgcn_s_waitcnt(0);
    __syncthreads();

    union { uint4 u; bf16x8 v; } z8; z8.u = (uint4){0u, 0u, 0u, 0u};
    #pragma unroll
    for (int t = 0; t < 2; ++t) {
      bf16x8 af[4], bf[4];
      #pragma unroll
      for (int mt = 0; mt < 4; ++mt) {
        af[mt] = *(const bf16x8*)(As + (wm * 64 + mt * 16 + ln15) * 64 + (((t * 4 + quad) ^ swz) * 8));
        if (!((sdr[mt] >> he) & 1)) af[mt] = z8.v;
      }
      #pragma unroll
      for (int nt = 0; nt < 4; ++nt)
        bf[nt] = *(const bf16x8*)(Bs + (wn * 64 + nt * 16 + ln15) * 64 + (((t * 4 + quad) ^ swz) * 8));
      #pragma unroll
      for (int mt = 0; mt < 4; ++mt)
        #pragma unroll
        for (int nt = 0; nt < 4; ++nt)
          acc[mt][nt] = __builtin_amdgcn_mfma_f32_16x16x32_bf16(af[mt], bf[nt], acc[mt][nt], 0, 0, 0);
    }
  }

  u16* Cz = Pk + (size_t)blockIdx.z * M_ * 1024;
  #pragma unroll
  for (int mt = 0; mt < 4; ++mt)
    #pragma unroll
    for (int nt = 0; nt < 4; ++nt)
      #pragma unroll
      for (int r = 0; r < 4; ++r) {
        int m = bm0 + wm * 64 + mt * 16 + quad * 4 + r;
        int n = bn0 + wn * 64 + nt * 16 + ln15;
        Cz[(size_t)m * 1024 + n] = f2bf(acc[mt][nt][r]);
      }
}

// reduce 4 bf16 split-K partials -> fp32 out
__global__ void reduce4_kernel(const u16* __restrict__ Pk, float* __restrict__ out) {
  int i = blockIdx.x * 256 + threadIdx.x;
  size_t base = (size_t)i * 8;
  float s[8] = {0.f, 0.f, 0.f, 0.f, 0.f, 0.f, 0.f, 0.f};
  #pragma unroll
  for (int z = 0; z < 4; ++z) {
    union { uint4 v; u16 h[8]; } u;
    u.v = *(const uint4*)(Pk + (size_t)z * M_ * 1024 + base);
    #pragma unroll
    for (int c = 0; c < 8; ++c) s[c] += bf2f(u.h[c]);
  }
  float4 o0 = {s[0], s[1], s[2], s[3]}, o1 = {s[4], s[5], s[6], s[7]};
  *(float4*)(out + base) = o0;
  *(float4*)(out + base + 4) = o1;
}

// ---------------- fused V-mix + transpose ----------------

__global__ __launch_bounds__(256)
void vmix_tr_kernel(const u16* __restrict__ c1, const float* __restrict__ ssg,
                    u16* __restrict__ vT) {
  __shared__ u16 tile[32][33];
  const int bh = blockIdx.x;
  const int b = bh >> 3, h = bh & 7;
  const int t0 = blockIdx.y * 32, d0 = blockIdx.z * 32;
  const int dh = threadIdx.x & 31, tl = threadIdx.x >> 5;
  #pragma unroll
  for (int i = 0; i < 4; ++i) {
    int trow = tl + i * 8;
    size_t bt = (size_t)b * T_ + t0 + trow;
    const u16* ve = c1 + bt * N1 + 1024 + h * (E_ * 64) + d0 + dh;
    const float* g = ssg + bt * 40 + h * E_;
    float s = 0.f;
    #pragma unroll
    for (int e = 0; e < E_; ++e) s = fmaf(g[e], bf2f(ve[e * 64]), s);
    tile[trow][dh] = f2bf(s);
  }
  __syncthreads();
  #pragma unroll
  for (int i = 0; i < 4; ++i) {
    int d = d0 + tl + i * 8;
    vT[((size_t)(b * H_ + h) * DH_ + d) * T_ + t0 + dh] = tile[dh][tl + i * 8];
  }
}

// ---------------- flash attention: CU-pair-balanced 32-row Q tiles, wave-pairs split kt ----------------

__global__ __launch_bounds__(256)
void attn_kernel(const u16* __restrict__ c1, const u16* __restrict__ vT,
                 u16* __restrict__ o_bh) {
  __shared__ __align__(16) u16 Qs[32 * 64];
  __shared__ __align__(16) u16 Ks[2][64 * 64];
  __shared__ __align__(16) u16 Vs[2][64 * 64];
  __shared__ __align__(16) u16 Ps[2][32 * 72];
  __shared__ float Om[2][32][68];
  __shared__ float Ml[2][32], Ll[2][32];
  // blocks L and L+256 co-locate on a CU (round-robin); they share bx and differ
  // by 8 in by, so qi(bx,by) + qi(bx,by+8) = 31 -> per-CU work ~constant.
  const int qi = (blockIdx.y < 8) ? blockIdx.x : (31 - blockIdx.x);
  const int bh = blockIdx.y;
  const int b = bh >> 3, h = bh & 7;
  const int tid = threadIdx.x;
  const int w = tid >> 6, lane = tid & 63;
  const int ln15 = lane & 15, quad = lane >> 4;
  const int hh = w >> 1, wq = w & 1;
  const int q0 = qi * 32;
  const int nkt = (qi >> 1) + 1;
  const int h0n = (nkt + 1) >> 1;
  const int r8 = lane >> 3;
  const int g8 = ((lane & 7) ^ ((lane >> 3) & 7)) * 8;
  const int swz = ln15 & 7;

  async_cp16(c1 + (size_t)(b * T_ + q0 + w * 8 + r8) * N1 + h * DH_ + g8,
             (char*)Qs + w * 1024);

  floatx4 O[4];
  float m_st[4], l_st[4];
  #pragma unroll
  for (int j = 0; j < 4; ++j) {
    O[j] = (floatx4){0.f, 0.f, 0.f, 0.f};
    m_st[j] = -3e38f; l_st[j] = 0.f;
  }
  const int qrow = q0 + wq * 16 + quad * 4;

  for (int j = 0; j < h0n; ++j) {
    const int myt = hh ? (h0n + j) : j;
    const bool act = (hh == 0) || (h0n + j < nkt);
    __syncthreads();
    if (w < 2 || h0n + j < nkt) {
      const int tk = (w < 2 ? j : h0n + j) * 64;
      if ((w & 1) == 0) {
        #pragma unroll
        for (int i = 0; i < 8; ++i)
          async_cp16(c1 + (size_t)(b * T_ + tk + i * 8 + r8) * N1 + 512 + h * DH_ + g8,
                     (char*)Ks[w >> 1] + i * 1024);
      } else {
        #pragma unroll
        for (int i = 0; i < 8; ++i)
          async_cp16(vT + (size_t)((b * H_ + h) * DH_ + i * 8 + r8) * T_ + tk + g8,
                     (char*)Vs[w >> 1] + i * 1024);
      }
    }
    __builtin_amdgcn_s_waitcnt(0);
    __syncthreads();

    float p[4][4];
    if (act) {
      const int tk0 = myt * 64;
      floatx4 S[4];
      #pragma unroll
      for (int nt = 0; nt < 4; ++nt) S[nt] = (floatx4){0.f, 0.f, 0.f, 0.f};
      #pragma unroll
      for (int ks = 0; ks < 2; ++ks) {
        bf16x8 a = *(const bf16x8*)(Qs + (wq * 16 + ln15) * 64 + (((ks * 4 + quad) ^ swz)) * 8);
        #pragma unroll
        for (int nt = 0; nt < 4; ++nt) {
          bf16x8 bv = *(const bf16x8*)(&Ks[hh][(nt * 16 + ln15) * 64 + (((ks * 4 + quad) ^ swz)) * 8]);
          S[nt] = __builtin_amdgcn_mfma_f32_16x16x32_bf16(a, bv, S[nt], 0, 0, 0);
        }
      }
      float rmax[4], alpha[4], rsum[4];
      #pragma unroll
      for (int r = 0; r < 4; ++r) rmax[r] = -3e38f;
      #pragma unroll
      for (int nt = 0; nt < 4; ++nt) {
        int col = tk0 + nt * 16 + ln15;
        #pragma unroll
        for (int r = 0; r < 4; ++r) {
          float s = S[nt][r] * 0.125f;
          if (col > qrow + r) s = -3e38f;
          p[nt][r] = s;
          rmax[r] = fmaxf(rmax[r], s);
        }
      }
      #pragma unroll
      for (int r = 0; r < 4; ++r) {
        #pragma unroll
        for (int off = 1; off < 16; off <<= 1)
          rmax[r] = fmaxf(rmax[r], __shfl_xor(rmax[r], off));
        float mn = fmaxf(m_st[r], rmax[r]);
        alpha[r] = __expf(m_st[r] - mn);
        m_st[r] = mn;
        rsum[r] = 0.f;
      }
      #pragma unroll
      for (int nt = 0; nt < 4; ++nt)
        #pragma unroll
        for (int r = 0; r < 4; ++r) {
          float e = __expf(p[nt][r] - m_st[r]);
          p[nt][r] = e;
          rsum[r] += e;
        }
      #pragma unroll
      for (int r = 0; r < 4; ++r) {
        #pragma unroll
        for (int off = 1; off < 16; off <<= 1)
          rsum[r] += __shfl_xor(rsum[r], off);
        l_st[r] = l_st[r] * alpha[r] + rsum[r];
      }
      #pragma unroll
      for (int nt = 0; nt < 4; ++nt)
        #pragma unroll
        for (int r = 0; r < 4; ++r) O[nt][r] *= alpha[r];
      #pragma unroll
      for (int nt = 0; nt < 4; ++nt)
        #pragma unroll
        for (int r = 0; r < 4; ++r)
          Ps[hh][(wq * 16 + quad * 4 + r) * 72 + nt * 16 + ln15] = f2bf(p[nt][r]);
    }
    __syncthreads();
    if (act) {
      #pragma unroll
      for (int ks = 0; ks < 2; ++ks) {
        bf16x8 a = *(const bf16x8*)(&Ps[hh][(wq * 16 + ln15) * 72 + ks * 32 + quad * 8]);
        #pragma unroll
        for (int nt = 0; nt < 4; ++nt) {
          bf16x8 bv = *(const bf16x8*)(&Vs[hh][(nt * 16 + ln15) * 64 + (((ks * 4 + quad) ^ swz)) * 8]);
          O[nt] = __builtin_amdgcn_mfma_f32_16x16x32_bf16(a, bv, O[nt], 0, 0, 0);
        }
      }
    }
  }

  #pragma unroll
  for (int nt = 0; nt < 4; ++nt)
    #pragma unroll
    for (int r = 0; r < 4; ++r)
      Om[hh][wq * 16 + quad * 4 + r][nt * 16 + ln15] = O[nt][r];
  if (ln15 == 0) {
    #pragma unroll
    for (int r = 0; r < 4; ++r) {
      Ml[hh][wq * 16 + quad * 4 + r] = m_st[r];
      Ll[hh][wq * 16 + quad * 4 + r] = l_st[r];
    }
  }
  __syncthreads();

  const int rr = tid >> 3, cg = (tid & 7) * 8;
  float m0 = Ml[0][rr], m1 = Ml[1][rr];
  float l0 = Ll[0][rr], l1 = Ll[1][rr];
  float m = fmaxf(m0, m1);
  float a0 = __expf(m0 - m), a1 = __expf(m1 - m);
  float inv = 1.f / (l0 * a0 + l1 * a1);
  union { u16 s[8]; uint4 v; } o;
  #pragma unroll
  for (int cc = 0; cc < 8; ++cc)
    o.s[cc] = f2bf((Om[0][rr][cg + cc] * a0 + Om[1][rr][cg + cc] * a1) * inv);
  *(uint4*)(o_bh + ((size_t)((b * 8 + h) * 1024 + q0 + rr)) * 64 + cg) = o.v;
}

// ---------------- launch ----------------

extern "C" void kernel_launch(void* const* d_in, const int* in_sizes, int n_in,
                              void* d_out, int out_size, void* d_ws, size_t ws_size,
                              hipStream_t stream) {
  const float* x  = (const float*)d_in[0];
  const float* Wq = (const float*)d_in[1];
  const float* Wk = (const float*)d_in[2];
  const float* Wv = (const float*)d_in[3];
  const float* Ws = (const float*)d_in[4];
  const float* Wd = (const float*)d_in[5];
  const float* Wo = (const float*)d_in[6];
  float* out = (float*)d_out;

  char* ws = (char*)d_ws;
  u16*   WoT  = (u16*)(ws + 0);            //  5,242,880
  u16*   xb   = (u16*)(ws + 5242880);      //  4,194,304
  u16*   WT   = (u16*)(ws + 9437184);      //  7,340,032  (end 16,777,216)
  u16*   c1   = (u16*)(ws + 16777216);     // 14,680,064  (end 31,457,280)
  float* ssg  = (float*)(ws + 31457280);   //    327,680
  u64*   sdb  = (u64*)(ws + 31784960);     //     16,384
  u16*   o_bh = (u16*)(ws + 31801344);     //  2,097,152  (end 33,898,496)
  u16*   vT   = (u16*)(ws + 33898496);     //  2,097,152  (end 35,995,648)
  u16*   Pk   = (u16*)(ws + 35995648);     // 16,777,216  (end 52,772,864)

  preamble_kernel<<<6400, 256, 0, stream>>>(x, Wq, Wk, Wv, Ws, Wd, Wo,
                                            WT, WoT, ssg, sdb, xb);

  // c1 = xb @ WT^T : M=2048, N=3584, K=1024, BK=64 (448 blocks)
  gemm4w_kernel<<<dim3(16, 28), 256, 0, stream>>>(xb, WT, c1, N1, 1024);

  vmix_tr_kernel<<<dim3(16, 32, 2), 256, 0, stream>>>(c1, ssg, vT);

  attn_kernel<<<dim3(32, 16), 256, 0, stream>>>(c1, vT, o_bh);

  // out = (sd ? o : 0) @ WoT^T : 128x128, split-K=4 (512 blocks)
  gemm2f_kernel<<<dim3(16, 8, 4), 256, 0, stream>>>(o_bh, WoT, sdb, Pk);
  reduce4_kernel<<<1024, 256, 0, stream>>>(Pk, out);
}